// Round 7
// baseline (218.598 us; speedup 1.0000x reference)
//
#include <hip/hip_runtime.h>

// SpikingLayer: T=64 sequential steps over [B=32, F=16384] fp32 state.
//   state = (x + state) - act
//   state = max(state + 1.0f, 0.0f) - 1.0f   // bit-exact relu(s+1)-1, NOT max(s,-1)
//   act   = state > 0 ? floor(state) : 0
// 134 MB in + 134 MB out; floor ~43 us @ 6.3 TB/s (less if L3 absorbs input).
//
// R2: float4, depth-2, 8 waves/CU  -> ~71 us   (latency-bound)
// R3: scalar, depth-8, 32 waves/CU -> ~82 us   (4x vmem instrs, worse)
// R6: float4, depth-8 + NT hints   -> ~60 us   (out of rocprof top-5)
// R7: depth-16 ring: 25k cycles load-to-use slack to ride out queued HBM
//     latency + in-order vmcnt retirement coupling loads to older store acks.

#define T_STEPS 64
#define NCHAINS (32 * 16384)       // B*F = 524288 independent chains
#define NCHAINS4 (NCHAINS / 4)     // float4 groups: 131072 threads
#define PF 16                      // prefetch ring depth (float4 -> 16 KB/wave)

typedef float vfloat4 __attribute__((ext_vector_type(4)));

__global__ __launch_bounds__(256) void spiking_kernel(
    const vfloat4* __restrict__ in, vfloat4* __restrict__ out) {
    const int i = blockIdx.x * blockDim.x + threadIdx.x;

    float s[4] = {0.f, 0.f, 0.f, 0.f};
    float a[4] = {0.f, 0.f, 0.f, 0.f};

    vfloat4 xs[PF];
    // prime the ring: 16 KB/wave in flight before any compute
    #pragma unroll
    for (int j = 0; j < PF; ++j)
        xs[j] = __builtin_nontemporal_load(&in[j * NCHAINS4 + i]);

    // fully unrolled: ring index + guard are compile-time static
    #pragma unroll
    for (int t = 0; t < T_STEPS; ++t) {
        vfloat4 x = xs[t % PF];
        if (t + PF < T_STEPS)
            xs[t % PF] = __builtin_nontemporal_load(&in[(t + PF) * NCHAINS4 + i]);

        float xe[4] = {x.x, x.y, x.z, x.w};
        #pragma unroll
        for (int e = 0; e < 4; ++e) {
            // EXACT ref op order: s = (x + s) - a; s = max(s+1,0)-1; a = spikes
            float sv = (xe[e] + s[e]) - a[e];
            sv = fmaxf(sv + 1.0f, 0.0f) - 1.0f;
            s[e] = sv;
            a[e] = (sv > 0.0f) ? floorf(sv) : 0.0f;
        }

        vfloat4 av = {a[0], a[1], a[2], a[3]};
        __builtin_nontemporal_store(av, &out[t * NCHAINS4 + i]);
    }
}

extern "C" void kernel_launch(void* const* d_in, const int* in_sizes, int n_in,
                              void* d_out, int out_size, void* d_ws, size_t ws_size,
                              hipStream_t stream) {
    const vfloat4* in = (const vfloat4*)d_in[0];
    vfloat4* out = (vfloat4*)d_out;
    // 131072 threads / 256 = 512 blocks -> 2 blocks/CU, 8 waves/CU
    spiking_kernel<<<NCHAINS4 / 256, 256, 0, stream>>>(in, out);
}